// Round 6
// baseline (510.229 us; speedup 1.0000x reference)
//
#include <hip/hip_runtime.h>

typedef __attribute__((ext_vector_type(4))) float f32x4;
typedef __attribute__((ext_vector_type(16))) float f32x16;
typedef __attribute__((ext_vector_type(4))) unsigned short u16x4;
typedef __attribute__((ext_vector_type(4))) int i32x4;
typedef __attribute__((ext_vector_type(8))) __bf16 bf16x8;

union FragAB {
  u16x4 u[2];
  i32x4 v;
  bf16x8 f;
};

static __device__ __forceinline__ unsigned short f2bf(float x) {
  union { float f; unsigned u; } v;
  v.f = x;
  unsigned r = v.u + 0x7FFFu + ((v.u >> 16) & 1u);  // round-to-nearest-even
  return (unsigned short)(r >> 16);
}

#define NN 8192

// ---------- kernel 1: prep (unchanged from round 5) ----------
__global__ __launch_bounds__(256) void k_prep(
    const int* __restrict__ adj, const float* __restrict__ V,
    const float* __restrict__ w1, const float* __restrict__ w2,
    const float* __restrict__ w3, const float* __restrict__ bias,
    unsigned char* __restrict__ adj2b, unsigned short* __restrict__ Vbp,
    unsigned short* __restrict__ Wbp, float* __restrict__ out) {
  int t = blockIdx.x * 256 + threadIdx.x;
  int nT = gridDim.x * 256;
  // (a) adj -> 2-bit byte pack (coalesced 16B reads, 1B stores)
  for (int g = t; g < 16777216; g += nT) {
    i32x4 a = *(const i32x4*)(adj + (size_t)g * 4);
    adj2b[g] = (unsigned char)((a.x & 3) | ((a.y & 3) << 2) |
                               ((a.z & 3) << 4) | ((a.w & 3) << 6));
  }
  // (b) V -> k-blocked bf16
  for (int g = t; g < 524288; g += nT) {
    int f = g * 4;
    int row = f >> 8, kcol = f & 255;
    f32x4 x = *(const f32x4*)(V + (size_t)f);
    u16x4 h;
    h.x = f2bf(x.x); h.y = f2bf(x.y); h.z = f2bf(x.z); h.w = f2bf(x.w);
    *(u16x4*)(Vbp + (size_t)(kcol >> 3) * 65536 + (size_t)row * 8 + (kcol & 7)) = h;
  }
  // (c) W -> k-blocked bf16
  for (int e = t; e < 65536; e += nT) {
    int k = e >> 8, n = e & 255;
    Wbp[(size_t)(k >> 3) * 6144 + (size_t)(0 * 256 + n) * 8 + (k & 7)] = f2bf(w1[e]);
  }
  for (int e = t; e < 65536; e += nT) {
    int k = e >> 8, n = e & 255;
    Wbp[(size_t)(k >> 3) * 6144 + (size_t)(1 * 256 + n) * 8 + (k & 7)] = f2bf(w2[e]);
  }
  for (int e = t; e < 65536; e += nT) {
    int k = e >> 8, n = e & 255;
    Wbp[(size_t)(k >> 3) * 6144 + (size_t)(2 * 256 + n) * 8 + (k & 7)] = f2bf(w3[e]);
  }
  // (d) out = bias broadcast
  for (int g = t; g < 524288; g += nT) {
    *(f32x4*)(out + (size_t)g * 4) = *(const f32x4*)(bias + ((g * 4) & 255));
  }
}

// ---------- kernel 2: Bp = (V @ Wcat)^T, reg GEMM (unchanged from round 5) ----------
// Bp element (ty, n, j) at  ty*2097152 + (j>>4)*4096 + n*16 + (j&15)  [verified].
__global__ __launch_bounds__(256) void k_transform(
    const unsigned short* __restrict__ Vbp, const unsigned short* __restrict__ Wbp,
    unsigned short* __restrict__ Bp) {
  int bx = blockIdx.x;
  int rb = bx & 127, nb = bx >> 7;
  int tid = threadIdx.x, lane = tid & 63;
  int wv = tid >> 6;
  int wr = wv >> 1, wc = wv & 1;
  int q = lane >> 4, l16 = lane & 15;

  f32x4 acc[2][4];
#pragma unroll
  for (int i = 0; i < 2; i++)
#pragma unroll
    for (int j = 0; j < 4; j++) acc[i][j] = (f32x4)0.0f;

  int r0 = rb * 64 + wr * 32 + l16;
  int n0 = nb * 128 + wc * 64 + l16;
  const unsigned short* av = Vbp + (size_t)q * 65536 + (size_t)r0 * 8;
  const unsigned short* bv = Wbp + (size_t)q * 6144 + (size_t)n0 * 8;

#pragma unroll 2
  for (int kk = 0; kk < 256; kk += 32) {
    FragAB af[2], bf[4];
#pragma unroll
    for (int mt = 0; mt < 2; mt++)
      af[mt].v = *(const i32x4*)(av + (size_t)(kk >> 3) * 65536 + mt * 128);
#pragma unroll
    for (int nt = 0; nt < 4; nt++)
      bf[nt].v = *(const i32x4*)(bv + (size_t)(kk >> 3) * 6144 + nt * 128);
#pragma unroll
    for (int mt = 0; mt < 2; mt++)
#pragma unroll
      for (int nt = 0; nt < 4; nt++)
        acc[mt][nt] = __builtin_amdgcn_mfma_f32_16x16x32_bf16(
            af[mt].f, bf[nt].f, acc[mt][nt], 0, 0, 0);
  }
#pragma unroll
  for (int mt = 0; mt < 2; mt++)
#pragma unroll
    for (int nt = 0; nt < 4; nt++) {
      int n = n0 + nt * 16;
      int ty = n >> 8, nn = n & 255;
      int j0 = rb * 64 + wr * 32 + mt * 16 + q * 4;
      u16x4 hv;
      hv.x = f2bf(acc[mt][nt].x);
      hv.y = f2bf(acc[mt][nt].y);
      hv.z = f2bf(acc[mt][nt].z);
      hv.w = f2bf(acc[mt][nt].w);
      size_t idx = (size_t)ty * 2097152 + (size_t)(j0 >> 4) * 4096 + nn * 16 + (j0 & 15);
      *(u16x4*)(Bp + idx) = hv;
    }
}

// ---------- kernel 3: out += sum_k (adj==k) @ H_k ----------
// v7: LDS-shared B, wave = 32 rows x 256 cols (C_w=256 -> MFMA >= mask-VALU),
// BM=128, BN=256, BK=16, splitK=8 -> 64 rb x 8 ks = 512 blocks (2/CU).
// Per step the block stages the 24 KB B-tile (3 ty x 8 KB contiguous Bp chunks)
// via reg-staging: 6x dwordx4 loads issued at step start (latency hidden under
// compute), ds_write after compute, double-buffered LDS (48 KB), ONE
// __syncthreads per step (vmcnt drain free: loads already consumed).
// Global B-traffic halves vs v6 (no wave duplication): 0.8 GB, ~23 us L2 floor.
// LDS read pattern verified conflict-optimal (8 lanes per bank-group).
__global__ __launch_bounds__(256, 2) void k_agg(const unsigned* __restrict__ adj2,
                                                const unsigned short* __restrict__ Bp,
                                                float* __restrict__ out) {
  int bx = blockIdx.x;
  int ks = bx & 7, rb = bx >> 3;
  int tid = threadIdx.x, lane = tid & 63;
  int wv = tid >> 6;  // 0..3: 32-row slab
  int q = lane >> 5, l32 = lane & 31;
  int qsh = q << 4;

  __shared__ unsigned short ldsB[2][12288];  // [buf][ty*4096 + n*16 + (k&15)]

  f32x16 acc[8];
#pragma unroll
  for (int nt = 0; nt < 8; nt++) acc[nt] = (f32x16)0.0f;

  int row = rb * 128 + wv * 32 + l32;
  const unsigned* ap = adj2 + (size_t)row * 512 + ks * 64;  // 64 step-dwords

  // 6 stage chunks of 16B/thread: chunk c covers bytes [c*4096, c*4096+4096)
  // of the 24KB step-image; ty = c>>1; source advances 8192 B per step.
  const char* Bpb = (const char*)Bp;
  const char* sp[6];
#pragma unroll
  for (int c = 0; c < 6; c++) {
    int ty = c >> 1;
    sp[c] = Bpb + (size_t)ty * 4194304 + (size_t)ks * 524288 + (c & 1) * 4096 +
            tid * 16;
  }

  // prologue: stage tile 0 into buf 0
  i32x4 rg[6];
#pragma unroll
  for (int c = 0; c < 6; c++) rg[c] = *(const i32x4*)sp[c];
#pragma unroll
  for (int c = 0; c < 6; c++)
    *(i32x4*)&ldsB[0][c * 2048 + tid * 8] = rg[c];
  unsigned cw = ap[0];
  __syncthreads();

  for (int s = 0; s < 64; ++s) {
    int cur = s & 1;
    if (s < 63) {  // issue next tile's 6 loads (consumed after compute)
#pragma unroll
      for (int c = 0; c < 6; c++)
        rg[c] = *(const i32x4*)(sp[c] + (size_t)(s + 1) * 8192);
    }
    unsigned nxc = (s < 63) ? ap[s + 1] : 0u;
    unsigned w = cw >> qsh;  // this lane's 8 codes (2 bits each)
    // compute: 3 ty x { 8 LDS B-frags, in-reg A mask, 8 MFMA }
#pragma unroll
    for (int ty = 0; ty < 3; ty++) {
      FragAB bv[8];
#pragma unroll
      for (int nt = 0; nt < 8; nt++)
        bv[nt].v = *(const i32x4*)&ldsB[cur][ty * 4096 + (nt * 32 + l32) * 16 + q * 8];
      FragAB A;
#pragma unroll
      for (int d = 0; d < 4; d++) {
        unsigned p0 = (w >> (4 * d)) & 3u, p1 = (w >> (4 * d + 2)) & 3u;
        A.v[d] = (int)((p0 == (unsigned)(ty + 1) ? 0x3F80u : 0u) |
                       (p1 == (unsigned)(ty + 1) ? 0x3F800000u : 0u));
      }
#pragma unroll
      for (int nt = 0; nt < 8; nt++)
        acc[nt] = __builtin_amdgcn_mfma_f32_32x32x16_bf16(A.f, bv[nt].f,
                                                          acc[nt], 0, 0, 0);
    }
    if (s < 63) {  // write next tile into the other buffer
#pragma unroll
      for (int c = 0; c < 6; c++)
        *(i32x4*)&ldsB[cur ^ 1][c * 2048 + tid * 8] = rg[c];
    }
    cw = nxc;
    __syncthreads();
  }
  // epilogue: C/D 32x32 layout col=lane&31, row=(reg&3)+8*(reg>>2)+4*q
#pragma unroll
  for (int nt = 0; nt < 8; nt++) {
    int col = nt * 32 + l32;
    int rowb = rb * 128 + wv * 32 + 4 * q;
#pragma unroll
    for (int r = 0; r < 16; r++) {
      int orow = rowb + (r & 3) + 8 * (r >> 2);
      atomicAdd(out + (size_t)orow * 256 + col, acc[nt][r]);
    }
  }
}

extern "C" void kernel_launch(void* const* d_in, const int* in_sizes, int n_in,
                              void* d_out, int out_size, void* d_ws,
                              size_t ws_size, hipStream_t stream) {
  const float* V = (const float*)d_in[0];
  const int* adj = (const int*)d_in[1];
  const float* w1 = (const float*)d_in[2];
  const float* w2 = (const float*)d_in[3];
  const float* w3 = (const float*)d_in[4];
  const float* bias = (const float*)d_in[5];
  float* out = (float*)d_out;
  // workspace layout:
  unsigned short* Bp = (unsigned short*)d_ws;                       // 12.58 MB @ 0
  unsigned char* adj2b = (unsigned char*)d_ws + 0xC00000;           // 16 MB
  unsigned short* Vbp = (unsigned short*)((char*)d_ws + 0x1C00000); // 4 MB
  unsigned short* Wbp = (unsigned short*)((char*)d_ws + 0x2000000); // 0.375 MB
  // total required: 0x2060000 = 33.9 MB

  k_prep<<<dim3(2048), dim3(256), 0, stream>>>(adj, V, w1, w2, w3, bias, adj2b,
                                               Vbp, Wbp, out);
  k_transform<<<dim3(768), dim3(256), 0, stream>>>(Vbp, Wbp, Bp);
  k_agg<<<dim3(512), dim3(256), 0, stream>>>((const unsigned*)adj2b, Bp, out);
}